// Round 9
// baseline (277.394 us; speedup 1.0000x reference)
//
#include <hip/hip_runtime.h>
#include <hip/hip_bf16.h>
#include <stdint.h>

typedef __bf16 bf16_t;
typedef bf16_t bf16x8 __attribute__((ext_vector_type(8)));
typedef float f32x4 __attribute__((ext_vector_type(4)));

#define D_IN 64
#define D_OUT 64
#define BM 128
#define NTHREADS 512

#define GLOAD_LDS16(gsrc, ldst)                                                     \
    __builtin_amdgcn_global_load_lds(                                               \
        (const __attribute__((address_space(1))) uint32_t*)(gsrc),                  \
        (__attribute__((address_space(3))) uint32_t*)(ldst), 16, 0, 0)

#define SBAR() __builtin_amdgcn_sched_barrier(0)

// XOR-swizzled byte offset into a [rows][64] bf16 tile (row stride 128 B).
__device__ __forceinline__ uint32_t swz(int row, int col) {
    return (uint32_t)((row * 128 + col * 2) ^ ((row & 7) << 4));
}

// ---------------- pre-pass 1: feats fp32 -> bf16 (+ zero row at index N) ----
__global__ void convert_feats(const float* __restrict__ feats,
                              bf16_t* __restrict__ fb,
                              int n_elems, int total8) {
    int g = blockIdx.x * blockDim.x + threadIdx.x;
    for (; g < total8; g += gridDim.x * blockDim.x) {
        const int e = g * 8;
        bf16x8 v = {};
        if (e < n_elems) {
            f32x4 a = *(const f32x4*)(feats + e);
            f32x4 b = *(const f32x4*)(feats + e + 4);
            #pragma unroll
            for (int i = 0; i < 4; ++i) {
                v[i]     = (bf16_t)a[i];
                v[i + 4] = (bf16_t)b[i];
            }
        }
        *(bf16x8*)(fb + e) = v;
    }
}

// ---------------- pre-pass 2: weight -> plain transposed bf16 wt[k][dp][d] --
__global__ void convert_weight(const float* __restrict__ w,
                               bf16_t* __restrict__ wt, int k3) {
    const int k = blockIdx.x;
    const int tid = threadIdx.x;              // 512
    const int dp = tid >> 3;
    const int d0 = (tid & 7) * 8;
    const float* src = w + (size_t)k * (D_IN * D_OUT) + (size_t)d0 * D_OUT + dp;
    bf16x8 v;
    #pragma unroll
    for (int j = 0; j < 8; ++j) v[j] = (bf16_t)src[j * D_OUT];
    *(bf16x8*)((char*)wt + (size_t)k * 8192 + dp * 128 + d0 * 2) = v;
}

// ---------------- main kernel: depth-2 pipeline at 3 blocks/CU --------------
// BM=128, A-only LDS TRIPLE buffer (48 KB). B in regs, loaded 2 iters ahead
// (3 named sets). Period-3 unrolled bodies; issue order pinned; counted
// vmcnt(8) + raw s_barrier per body -> stage(k+1) stays in flight across
// the barrier (true depth-2). 8 waves as 2(row)x4(col): 64 rows x 16 cols,
// acc[4].
__global__ __launch_bounds__(NTHREADS, 6) void subm_conv_d2(
    const bf16_t* __restrict__ fb,      // (N+1) rows x 128 B, row N = zeros
    const int* __restrict__ indices,
    const bf16_t* __restrict__ wt,      // [k3][64][64] bf16, wt[k][dp][d]
    float* __restrict__ out,
    int n_vox, int k3)
{
    __shared__ __align__(16) bf16_t As[3][BM * 64];   // 3 x 16 KB = 48 KB

    const int tid  = threadIdx.x;
    const int lane = tid & 63;
    const int wv   = tid >> 6;
    const int l15  = lane & 15;
    const int l4   = lane >> 4;
    const int wr   = (wv & 1) * 64;     // wave row base: 0 or 64
    const int wc   = (wv >> 1) * 16;    // wave col base: 0,16,32,48
    const int n0   = blockIdx.x * BM;

    // A-staging: wave wv stages rows [wv*16, wv*16+16) = 2 issues of 8 rows.
    const int rA0 = wv * 16 + (lane >> 3);
    const int rA1 = rA0 + 8;
    const int cp  = lane & 7;
    const uint32_t so0 = (uint32_t)((cp ^ (rA0 & 7)) * 16);
    const uint32_t so1 = (uint32_t)((cp ^ (rA1 & 7)) * 16);

    int    ia[3][2];       // idx sets: idx(j) lives in set j%3
    bf16x8 Bf[3][2];       // B sets:   B(j)  lives in set j%3

    #define KCLAMP(x) ((x) < k3 ? (x) : k3 - 1)

    #define LOADIDX(kk, s) do {                                                \
        const int kc_ = KCLAMP(kk);                                            \
        const int* ip_ = indices + (size_t)kc_ * n_vox + n0;                   \
        ia[s][0] = (n0 + rA0 < n_vox) ? ip_[rA0] : -1;                         \
        ia[s][1] = (n0 + rA1 < n_vox) ? ip_[rA1] : -1;                         \
    } while (0)

    #define STAGE(bs, s) do {                                                  \
        const size_t r0_ = (size_t)((ia[s][0] >= 0 && ia[s][0] < n_vox) ? ia[s][0] : n_vox); \
        const size_t r1_ = (size_t)((ia[s][1] >= 0 && ia[s][1] < n_vox) ? ia[s][1] : n_vox); \
        char* ad_ = (char*)&As[bs][0] + wv * 2048;                             \
        GLOAD_LDS16((const char*)fb + r0_ * 128 + so0, ad_);                   \
        GLOAD_LDS16((const char*)fb + r1_ * 128 + so1, ad_ + 1024);            \
    } while (0)

    #define LOADB(s, kk) do {                                                  \
        const int kc_ = KCLAMP(kk);                                            \
        const char* wb_ = (const char*)wt + (size_t)kc_ * 8192                 \
                        + (size_t)(wc + l15) * 128 + l4 * 16;                  \
        Bf[s][0] = *(const bf16x8*)(wb_);                                      \
        Bf[s][1] = *(const bf16x8*)(wb_ + 64);                                 \
    } while (0)

    f32x4 acc[4];
    #pragma unroll
    for (int i = 0; i < 4; ++i)
        acc[i] = (f32x4){0.f, 0.f, 0.f, 0.f};

    // ---- prologue (issue order pinned; matches steady-state ledger) ----
    // order: idx0, idx1, stage0, idx2, stage1, B0, B1
    LOADIDX(0, 0); LOADIDX(1, 1);
    SBAR(); STAGE(0, 0);
    SBAR(); LOADIDX(2, 2);
    SBAR(); STAGE(1, 1);
    SBAR(); LOADB(0, 0); LOADB(1, 1);
    SBAR();

    const int kmain = k3 - (k3 % 3);

    // ---- main loop: period-3 bodies, all slot indices compile-time --------
    for (int kb = 0; kb + 3 <= kmain; kb += 3) {
        #pragma unroll
        for (int p = 0; p < 3; ++p) {
            const int k = kb + p;
            // stage(k) has exactly 8 newer VMEM ops: B(k):2 + body(k-1):6.
            asm volatile("s_waitcnt vmcnt(8)" ::: "memory");
            __builtin_amdgcn_s_barrier();
            SBAR();
            // pinned issue order: idx(k+3) ; stageA(k+2) ; B(k+2)
            LOADIDX(k + 3, p);
            SBAR();
            STAGE((p + 2) % 3, (p + 2) % 3);
            SBAR();
            LOADB((p + 2) % 3, k + 2);
            SBAR();
            // MFMA from As[p], Bf[p]
            const char* ab = (const char*)&As[p][0];
            #pragma unroll
            for (int ks = 0; ks < 2; ++ks) {
                #pragma unroll
                for (int mi = 0; mi < 4; ++mi) {
                    bf16x8 a = *(const bf16x8*)(ab + swz(wr + mi * 16 + l15, ks * 32 + l4 * 8));
                    acc[mi] = __builtin_amdgcn_mfma_f32_16x16x32_bf16(a, Bf[p][ks], acc[mi], 0, 0, 0);
                }
            }
        }
    }

    // ---- generic tail (k3 % 3 != 0; empty for k3 = 27) --------------------
    for (int k = kmain; k < k3; ++k) {
        asm volatile("s_waitcnt vmcnt(0)" ::: "memory");
        __syncthreads();
        LOADIDX(k, 0);
        STAGE(0, 0);
        LOADB(0, k);
        asm volatile("s_waitcnt vmcnt(0)" ::: "memory");
        __syncthreads();
        const char* ab = (const char*)&As[0][0];
        #pragma unroll
        for (int ks = 0; ks < 2; ++ks) {
            #pragma unroll
            for (int mi = 0; mi < 4; ++mi) {
                bf16x8 a = *(const bf16x8*)(ab + swz(wr + mi * 16 + l15, ks * 32 + l4 * 8));
                acc[mi] = __builtin_amdgcn_mfma_f32_16x16x32_bf16(a, Bf[0][ks], acc[mi], 0, 0, 0);
            }
        }
    }

    // C/D layout: col = lane&15, row = (lane>>4)*4 + reg
    #pragma unroll
    for (int mi = 0; mi < 4; ++mi)
        #pragma unroll
        for (int j = 0; j < 4; ++j) {
            const int row = n0 + wr + mi * 16 + l4 * 4 + j;
            const int col = wc + l15;
            if (row < n_vox)
                out[(size_t)row * D_OUT + col] = acc[mi][j];
        }
    #undef LOADIDX
    #undef STAGE
    #undef LOADB
    #undef KCLAMP
}

// ---------------- fallback (round-1 kernel) --------------------------------
__global__ __launch_bounds__(512, 1) void subm_conv_mfma_v1(
    const float* __restrict__ feats,
    const int* __restrict__ indices,
    const float* __restrict__ weight,
    float* __restrict__ out,
    int n_vox, int k3)
{
    __shared__ bf16_t As[128 * 64];
    __shared__ bf16_t Bs[64 * 64];

    const int tid  = threadIdx.x;
    const int lane = tid & 63;
    const int wv   = tid >> 6;
    const int wr   = (wv >> 1) * 32;
    const int wc   = (wv & 1) * 32;
    const int l15  = lane & 15;
    const int l4   = lane >> 4;
    const int n0   = blockIdx.x * 128;

    const int ar = tid >> 2;
    const int ac = (tid & 3) * 16;
    const int bdp = tid & 63;
    const int bd0 = (tid >> 6) * 8;

    f32x4 acc[2][2];
    #pragma unroll
    for (int i = 0; i < 2; ++i)
        #pragma unroll
        for (int j = 0; j < 2; ++j)
            acc[i][j] = (f32x4){0.f, 0.f, 0.f, 0.f};

    for (int k = 0; k < k3; ++k) {
        __syncthreads();
        {
            const int n = n0 + ar;
            int idx = (n < n_vox) ? indices[(size_t)k * n_vox + n] : -1;
            bf16x8 v0 = {}, v1 = {};
            if (idx >= 0) {
                const float* src = feats + (size_t)idx * D_IN + ac;
                f32x4 f0 = *(const f32x4*)(src + 0);
                f32x4 f1 = *(const f32x4*)(src + 4);
                f32x4 f2 = *(const f32x4*)(src + 8);
                f32x4 f3 = *(const f32x4*)(src + 12);
                #pragma unroll
                for (int i = 0; i < 4; ++i) {
                    v0[i]     = (bf16_t)f0[i];
                    v0[i + 4] = (bf16_t)f1[i];
                    v1[i]     = (bf16_t)f2[i];
                    v1[i + 4] = (bf16_t)f3[i];
                }
            }
            *(bf16x8*)((char*)As + swz(ar, ac))     = v0;
            *(bf16x8*)((char*)As + swz(ar, ac + 8)) = v1;
        }
        {
            const float* wsrc = weight + (size_t)k * (D_IN * D_OUT) + (size_t)bd0 * D_OUT + bdp;
            bf16x8 v;
            #pragma unroll
            for (int i = 0; i < 8; ++i) v[i] = (bf16_t)wsrc[i * D_OUT];
            *(bf16x8*)((char*)Bs + swz(bdp, bd0)) = v;
        }
        __syncthreads();
        #pragma unroll
        for (int ks = 0; ks < 2; ++ks) {
            const int kc = ks * 32 + l4 * 8;
            bf16x8 a0 = *(const bf16x8*)((char*)As + swz(wr + l15,      kc));
            bf16x8 a1 = *(const bf16x8*)((char*)As + swz(wr + 16 + l15, kc));
            bf16x8 b0 = *(const bf16x8*)((char*)Bs + swz(wc + l15,      kc));
            bf16x8 b1 = *(const bf16x8*)((char*)Bs + swz(wc + 16 + l15, kc));
            acc[0][0] = __builtin_amdgcn_mfma_f32_16x16x32_bf16(a0, b0, acc[0][0], 0, 0, 0);
            acc[0][1] = __builtin_amdgcn_mfma_f32_16x16x32_bf16(a0, b1, acc[0][1], 0, 0, 0);
            acc[1][0] = __builtin_amdgcn_mfma_f32_16x16x32_bf16(a1, b0, acc[1][0], 0, 0, 0);
            acc[1][1] = __builtin_amdgcn_mfma_f32_16x16x32_bf16(a1, b1, acc[1][1], 0, 0, 0);
        }
    }

    #pragma unroll
    for (int mi = 0; mi < 2; ++mi)
        #pragma unroll
        for (int ni = 0; ni < 2; ++ni)
            #pragma unroll
            for (int j = 0; j < 4; ++j) {
                const int row = n0 + wr + mi * 16 + l4 * 4 + j;
                const int col = wc + ni * 16 + l15;
                if (row < n_vox)
                    out[(size_t)row * D_OUT + col] = acc[mi][ni][j];
            }
}

extern "C" void kernel_launch(void* const* d_in, const int* in_sizes, int n_in,
                              void* d_out, int out_size, void* d_ws, size_t ws_size,
                              hipStream_t stream) {
    const float* feats   = (const float*)d_in[0];
    const int*   indices = (const int*)d_in[1];
    const float* weight  = (const float*)d_in[2];
    float* out = (float*)d_out;

    const int n_vox = in_sizes[0] / D_IN;
    const int k3    = in_sizes[2] / (D_IN * D_OUT);

    const size_t fb_bytes  = (size_t)(n_vox + 1) * D_IN * sizeof(bf16_t);
    const size_t wt_off    = (fb_bytes + 255) & ~(size_t)255;
    const size_t wt_bytes  = (size_t)k3 * 64 * 64 * sizeof(bf16_t);
    const size_t need      = wt_off + wt_bytes;

    if (ws_size >= need && k3 >= 3) {
        bf16_t* fb = (bf16_t*)((char*)d_ws);
        bf16_t* wt = (bf16_t*)((char*)d_ws + wt_off);

        const int n_elems = n_vox * D_IN;
        const int total8  = (n_vox + 1) * (D_IN / 8);
        int cblocks = (total8 + 255) / 256;
        if (cblocks > 2048) cblocks = 2048;
        convert_feats<<<cblocks, 256, 0, stream>>>(feats, fb, n_elems, total8);
        convert_weight<<<k3, 512, 0, stream>>>(weight, wt, k3);

        const int grid = (n_vox + BM - 1) / BM;
        subm_conv_d2<<<grid, NTHREADS, 0, stream>>>(fb, indices, wt, out, n_vox, k3);
    } else {
        const int grid = (n_vox + 127) / 128;
        subm_conv_mfma_v1<<<grid, 512, 0, stream>>>(feats, indices, weight, out, n_vox, k3);
    }
}